// Round 2
// baseline (516.038 us; speedup 1.0000x reference)
//
#include <hip/hip_runtime.h>

#define T_STEPS 1024
#define CC 6
#define NCHUNK 8
#define CHUNK (T_STEPS / NCHUNK)   // 128
#define WARM 16                    // warm-up steps per chunk (error ~0.08^15)
#define LOG2E 1.4426950408889634f
#define LN2   0.6931471805599453f

__device__ __forceinline__ float fexp2(float x) {
#if __has_builtin(__builtin_amdgcn_exp2f)
    return __builtin_amdgcn_exp2f(x);
#else
    return exp2f(x);
#endif
}

__device__ __forceinline__ float flog2(float x) {
#if __has_builtin(__builtin_amdgcn_logf)
    return __builtin_amdgcn_logf(x);   // v_log_f32 = log2
#else
    return log2f(x);
#endif
}

// broadcast value from lane ((lane & ~7) | i) within each 8-lane group
template <int I>
__device__ __forceinline__ float group_bcast(float v) {
#if __has_builtin(__builtin_amdgcn_ds_swizzle)
    return __int_as_float(__builtin_amdgcn_ds_swizzle(__float_as_int(v), (I << 5) | 0x18));
#else
    return __shfl(v, I, 8);
#endif
}

// One 8-lane group per (batch row, time-chunk). Lane j (0..5) owns channel j;
// lanes 6,7 shadow lane 5 so the wave never diverges. Chunks c>0 warm up for
// WARM steps seeded with state = x at t0-WARM: the recurrence contracts by
// (1-a)*max(Tn) ~ 0.08 per step, so the seed error is < 1e-16 by chunk start.
__global__ __launch_bounds__(256, 1) void transfer_kernel(
    const float* __restrict__ feats,
    const float* __restrict__ alpha,
    const float* __restrict__ trans,
    float* __restrict__ out, int B)
{
    int tid = blockIdx.x * blockDim.x + threadIdx.x;
    int g   = tid >> 3;
    int j   = tid & 7;
    int jl  = j < CC ? j : (CC - 1);
    if (g >= B * NCHUNK) return;

    int b = g % B;   // consecutive groups -> consecutive rows (coalesced, like round 0)
    int c = g / B;   // wave-uniform chunk index (B % 8 == 0 -> no wave straddles)

    // a = sigmoid(alpha)
    float a  = 1.0f / (1.0f + fexp2(-alpha[0] * LOG2E));
    float c1 = (1.0f - a) * LN2;   // (1-a) * ln2: converts log2-sum to natural te

    // column jl of row-softmax(trans), pre-scaled by log2e
    float tcol[CC];
#pragma unroll
    for (int i = 0; i < CC; ++i) {
        float rs = 0.0f;
#pragma unroll
        for (int k = 0; k < CC; ++k)
            rs += fexp2(trans[i * CC + k] * LOG2E);
        tcol[i] = (fexp2(trans[i * CC + jl] * LOG2E) / rs) * LOG2E;
    }

    const float* fb = feats + (size_t)b * T_STEPS * CC;
    float*       ob = out   + (size_t)b * T_STEPS * CC;

#define STEP(xv)                                              \
    do {                                                      \
        float sum;                                            \
        sum  = fexp2(group_bcast<0>(state) * tcol[0]);        \
        sum += fexp2(group_bcast<1>(state) * tcol[1]);        \
        sum += fexp2(group_bcast<2>(state) * tcol[2]);        \
        sum += fexp2(group_bcast<3>(state) * tcol[3]);        \
        sum += fexp2(group_bcast<4>(state) * tcol[4]);        \
        sum += fexp2(group_bcast<5>(state) * tcol[5]);        \
        state = a * (xv) + c1 * flog2(sum);                   \
    } while (0)

    int t0   = c * CHUNK;
    int tend = t0 + CHUNK;   // exclusive
    float state;
    int   tmain;             // first emitted step computed in the main loop

    if (c == 0) {
        // exact: t=0 emits feats as-is
        state  = fb[jl];
        ob[jl] = state;
        tmain  = 1;
    } else {
        // speculative warm-up: seed with x at t0-WARM, run WARM-1 steps
        int tw = t0 - WARM;   // >= 112, always in-bounds
        state  = fb[tw * CC + jl];
#pragma unroll
        for (int t = 0; t < WARM - 1; ++t) {
            float x = fb[(tw + 1 + t) * CC + jl];
            STEP(x);
        }
        tmain = t0;
    }

    // main loop with one-step prefetch; final step peeled (no read past chunk)
    float x_next = fb[tmain * CC + jl];
#pragma unroll 4
    for (int t = tmain; t < tend - 1; ++t) {
        float x = x_next;
        x_next  = fb[(t + 1) * CC + jl];
        STEP(x);
        ob[t * CC + jl] = state;
    }
    {
        float x = x_next;
        STEP(x);
        ob[(tend - 1) * CC + jl] = state;
    }
#undef STEP
}

extern "C" void kernel_launch(void* const* d_in, const int* in_sizes, int n_in,
                              void* d_out, int out_size, void* d_ws, size_t ws_size,
                              hipStream_t stream) {
    const float* feats = (const float*)d_in[0];
    const float* alpha = (const float*)d_in[1];
    const float* trans = (const float*)d_in[2];
    float* out = (float*)d_out;

    int B = in_sizes[0] / (T_STEPS * CC);   // 8192 (same convention as verified round-0 kernel)

    int threads = B * NCHUNK * 8;           // 8 lanes per (row, chunk)
    int block   = 256;
    int grid    = (threads + block - 1) / block;

    hipLaunchKernelGGL(transfer_kernel, dim3(grid), dim3(block), 0, stream,
                       feats, alpha, trans, out, B);
}

// Round 3
// 360.710 us; speedup vs baseline: 1.4306x; 1.4306x over previous
//
#include <hip/hip_runtime.h>

#define T_STEPS 1024
#define CC 6
#define NCHUNK 8
#define CHUNK (T_STEPS / NCHUNK)   // 128
#define WARM 16                    // warm-up steps per chunk (error ~0.08^15)
#define KBUF 16                    // steps buffered in LDS before each flush
#define NBLK (CHUNK / KBUF)        // 8 flush blocks per chunk
#define GPAD 100                   // dwords per group in LDS (96 used + 4 pad -> bank spread)
#define LOG2E 1.4426950408889634f
#define LN2   0.6931471805599453f

__device__ __forceinline__ float fexp2(float x) {
#if __has_builtin(__builtin_amdgcn_exp2f)
    return __builtin_amdgcn_exp2f(x);
#else
    return exp2f(x);
#endif
}

__device__ __forceinline__ float flog2(float x) {
#if __has_builtin(__builtin_amdgcn_logf)
    return __builtin_amdgcn_logf(x);   // v_log_f32 = log2
#else
    return log2f(x);
#endif
}

// broadcast value from lane ((lane & ~7) | i) within each 8-lane group
template <int I>
__device__ __forceinline__ float group_bcast(float v) {
#if __has_builtin(__builtin_amdgcn_ds_swizzle)
    return __int_as_float(__builtin_amdgcn_ds_swizzle(__float_as_int(v), (I << 5) | 0x18));
#else
    return __shfl(v, I, 8);
#endif
}

// One 8-lane group per (batch row, time-chunk). Lane j (0..5) owns channel j;
// lanes 6,7 shadow lane 5 during compute (identical math, no divergence) and
// do real work during the flush. Chunks c>0 warm up for WARM steps seeded with
// state = x at t0-WARM: per-step contraction (1-a)*max(Tn) ~ 0.08 makes the
// seed error < 1e-16 by chunk start.
//
// Output is buffered in LDS for KBUF=16 steps (384 B per group, 128-aligned in
// the output row) and flushed as 3 full 128-B-line dwordx4 stores per group --
// this kills the 2.3x partial-line write amplification seen in round 2.
__global__ __launch_bounds__(256, 8) void transfer_kernel(
    const float* __restrict__ feats,
    const float* __restrict__ alpha,
    const float* __restrict__ trans,
    float* __restrict__ out, int B)
{
    __shared__ float sbuf[32 * GPAD];   // 32 groups/block * 400 B = 12.8 KB

    int tid = blockIdx.x * blockDim.x + threadIdx.x;
    int g   = tid >> 3;                 // global group id
    int gb  = (threadIdx.x >> 3);       // group id within block (0..31)
    int j   = tid & 7;
    int jl  = j < CC ? j : (CC - 1);
    if (g >= B * NCHUNK) return;

    int b = g % B;   // consecutive groups -> consecutive rows (coalesced reads)
    int c = g / B;   // wave-uniform chunk index (B % 8 == 0 -> no wave straddles)

    // a = sigmoid(alpha)
    float a  = 1.0f / (1.0f + fexp2(-alpha[0] * LOG2E));
    float c1 = (1.0f - a) * LN2;   // (1-a) * ln2: converts log2-sum to natural te

    // column jl of row-softmax(trans), pre-scaled by log2e
    float tcol[CC];
#pragma unroll
    for (int i = 0; i < CC; ++i) {
        float rs = 0.0f;
#pragma unroll
        for (int k = 0; k < CC; ++k)
            rs += fexp2(trans[i * CC + k] * LOG2E);
        tcol[i] = (fexp2(trans[i * CC + jl] * LOG2E) / rs) * LOG2E;
    }

    const float* fb = feats + (size_t)b * T_STEPS * CC;
    float*       ob = out   + (size_t)b * T_STEPS * CC;

#define STEP(xv)                                              \
    do {                                                      \
        float sum;                                            \
        sum  = fexp2(group_bcast<0>(state) * tcol[0]);        \
        sum += fexp2(group_bcast<1>(state) * tcol[1]);        \
        sum += fexp2(group_bcast<2>(state) * tcol[2]);        \
        sum += fexp2(group_bcast<3>(state) * tcol[3]);        \
        sum += fexp2(group_bcast<4>(state) * tcol[4]);        \
        sum += fexp2(group_bcast<5>(state) * tcol[5]);        \
        state = a * (xv) + c1 * flog2(sum);                   \
    } while (0)

    int t0 = c * CHUNK;
    float state;

    if (c != 0) {
        // speculative warm-up: seed with x at t0-WARM, run WARM-1 steps
        int tw = t0 - WARM;   // >= 112, always in-bounds
        state  = fb[tw * CC + jl];
#pragma unroll
        for (int t = 0; t < WARM - 1; ++t) {
            float x = fb[(tw + 1 + t) * CC + jl];
            STEP(x);
        }
    }
    // (for c == 0, state is initialized at t = 0 inside the first block)

#pragma unroll 1
    for (int kb = 0; kb < NBLK; ++kb) {
        int tbase = t0 + kb * KBUF;

        // compute KBUF steps, buffering states in LDS
#pragma unroll
        for (int kk = 0; kk < KBUF; ++kk) {
            float x = fb[(tbase + kk) * CC + jl];
            if (kk == 0 && kb == 0 && c == 0) {
                state = x;                // t = 0: emit feats as-is
            } else {
                STEP(x);
            }
            sbuf[gb * GPAD + kk * CC + jl] = state;  // lanes 6,7: same addr+value as lane 5
        }

        // flush: 96 dwords per group = 3 x (8 lanes x float4), each a full
        // 128-B-aligned line. Intra-wave LDS RAW: DS pipe is in-order per wave.
        int obase = tbase * CC;           // dword offset; byte = 3072c + 384kb (128-aligned)
#pragma unroll
        for (int k = 0; k < 3; ++k) {
            int idx = (k * 8 + j) * 4;    // dword within the group's 96
            float4 v = *reinterpret_cast<const float4*>(&sbuf[gb * GPAD + idx]);
            *reinterpret_cast<float4*>(&ob[obase + idx]) = v;
        }
    }
#undef STEP
}

extern "C" void kernel_launch(void* const* d_in, const int* in_sizes, int n_in,
                              void* d_out, int out_size, void* d_ws, size_t ws_size,
                              hipStream_t stream) {
    const float* feats = (const float*)d_in[0];
    const float* alpha = (const float*)d_in[1];
    const float* trans = (const float*)d_in[2];
    float* out = (float*)d_out;

    int B = in_sizes[0] / (T_STEPS * CC);   // 8192 (same convention as verified round-0 kernel)

    int threads = B * NCHUNK * 8;           // 8 lanes per (row, chunk)
    int block   = 256;
    int grid    = (threads + block - 1) / block;

    hipLaunchKernelGGL(transfer_kernel, dim3(grid), dim3(block), 0, stream,
                       feats, alpha, trans, out, B);
}

// Round 4
// 359.261 us; speedup vs baseline: 1.4364x; 1.0040x over previous
//
#include <hip/hip_runtime.h>

#define T_STEPS 1024
#define CC 6
#define NCHUNK 8
#define CHUNK (T_STEPS / NCHUNK)   // 128
#define WARM 16                    // warm-up steps per chunk (error ~0.08^15)
#define KBUF 16                    // steps buffered in LDS before each flush
#define NBLK (CHUNK / KBUF)        // 8 flush blocks per chunk
#define GPAD 100                   // dwords per group in LDS (96 used + 4 pad)
#define LOG2E 1.4426950408889634f
#define LN2   0.6931471805599453f

__device__ __forceinline__ float fexp2(float x) {
#if __has_builtin(__builtin_amdgcn_exp2f)
    return __builtin_amdgcn_exp2f(x);
#else
    return exp2f(x);
#endif
}

__device__ __forceinline__ float flog2(float x) {
#if __has_builtin(__builtin_amdgcn_logf)
    return __builtin_amdgcn_logf(x);   // v_log_f32 = log2
#else
    return log2f(x);
#endif
}

// One 8-lane group per (batch row, time-chunk). Lane j (0..5) owns channel j;
// lanes 6,7 shadow lane 5 (identical math, same-address LDS writes) so the
// wave never diverges. Chunks c>0 warm up WARM steps seeded with state = x at
// t0-WARM: per-step contraction (1-a)*max(Tn) ~ 0.08 -> seed error < 1e-16.
//
// DS-pipe diet (round 4): state broadcast via 6 ds_swizzle/step replaced by
// reading the PREVIOUS step's 6-float state vector straight out of the LDS
// output buffer we write anyway: 1 ds_write_b32 + ~2 vector ds_reads per step
// instead of 7 DS ops. DS pipe is per-CU and was the binding pipe at 32
// waves/CU. Intra-wave RAW through LDS is safe: DS pipe is in-order per wave.
//
// Output buffered KBUF=16 steps (384 B/group, 128-aligned) and flushed as
// 3 full-line dwordx4 stores per group (round-3 fix for write amplification).
__global__ __launch_bounds__(256, 8) void transfer_kernel(
    const float* __restrict__ feats,
    const float* __restrict__ alpha,
    const float* __restrict__ trans,
    float* __restrict__ out, int B)
{
    __shared__ float sbuf[32 * GPAD];   // 32 groups/block * 400 B = 12.8 KB

    int tid = blockIdx.x * blockDim.x + threadIdx.x;
    int g   = tid >> 3;                 // global group id
    int gb  = (threadIdx.x >> 3);       // group id within block (0..31)
    int j   = tid & 7;
    int jl  = j < CC ? j : (CC - 1);
    if (g >= B * NCHUNK) return;

    int b = g % B;   // consecutive groups -> consecutive rows (coalesced reads)
    int c = g / B;   // wave-uniform chunk index (B % 8 == 0 -> no wave straddles)

    // a = sigmoid(alpha)
    float a  = 1.0f / (1.0f + fexp2(-alpha[0] * LOG2E));
    float c1 = (1.0f - a) * LN2;   // (1-a) * ln2: converts log2-sum to natural te

    // column jl of row-softmax(trans), pre-scaled by log2e
    float tcol[CC];
#pragma unroll
    for (int i = 0; i < CC; ++i) {
        float rs = 0.0f;
#pragma unroll
        for (int k = 0; k < CC; ++k)
            rs += fexp2(trans[i * CC + k] * LOG2E);
        tcol[i] = (fexp2(trans[i * CC + jl] * LOG2E) / rs) * LOG2E;
    }

    const float* fb = feats + (size_t)b * T_STEPS * CC;
    float*       ob = out   + (size_t)b * T_STEPS * CC;
    float*       sg = &sbuf[gb * GPAD];   // this group's LDS region

    // read previous step's full state vector from LDS slot PSLOT, advance one
    // step. All addresses 8-B aligned (GPAD and CC*PSLOT both even).
#define STEP_LDS(PSLOT, xv)                                              \
    do {                                                                 \
        float2 s01 = *reinterpret_cast<const float2*>(&sg[(PSLOT) * CC + 0]); \
        float2 s23 = *reinterpret_cast<const float2*>(&sg[(PSLOT) * CC + 2]); \
        float2 s45 = *reinterpret_cast<const float2*>(&sg[(PSLOT) * CC + 4]); \
        float sum;                                                       \
        sum  = fexp2(s01.x * tcol[0]);                                   \
        sum += fexp2(s01.y * tcol[1]);                                   \
        sum += fexp2(s23.x * tcol[2]);                                   \
        sum += fexp2(s23.y * tcol[3]);                                   \
        sum += fexp2(s45.x * tcol[4]);                                   \
        sum += fexp2(s45.y * tcol[5]);                                   \
        state = a * (xv) + c1 * flog2(sum);                              \
    } while (0)

    int t0 = c * CHUNK;
    float state;

    if (c != 0) {
        // speculative warm-up: seed -> slot 0; step w reads slot w-1, writes
        // slot w; after w=WARM-1 the state for t0-1 sits in slot WARM-1 = 15.
        int tw = t0 - WARM;   // >= 112, always in-bounds
        state  = fb[tw * CC + jl];
        sg[0 * CC + jl] = state;
#pragma unroll
        for (int w = 1; w < WARM; ++w) {
            float x = fb[(tw + w) * CC + jl];
            STEP_LDS(w - 1, x);
            sg[w * CC + jl] = state;
        }
    }
    // (for c == 0, state is initialized at t = 0 inside the first block)

#pragma unroll 1
    for (int kb = 0; kb < NBLK; ++kb) {
        int tbase = t0 + kb * KBUF;

        // compute KBUF steps; each step reads prev slot, writes its own slot
#pragma unroll
        for (int kk = 0; kk < KBUF; ++kk) {
            float x = fb[(tbase + kk) * CC + jl];
            if (kk == 0) {
                if (kb == 0 && c == 0) {
                    state = x;                 // t = 0: emit feats as-is
                } else {
                    STEP_LDS(KBUF - 1, x);     // prev block's (or warm-up's) slot 15
                }
            } else {
                STEP_LDS(kk - 1, x);
            }
            sg[kk * CC + jl] = state;  // lanes 6,7: same addr+value as lane 5
        }

        // flush: 96 dwords per group = 3 x (8 lanes x float4), each a full
        // 128-B-aligned line. Intra-wave LDS RAW: DS pipe is in-order per wave.
        int obase = tbase * CC;        // byte = 3072c + 384kb -> 128-aligned
#pragma unroll
        for (int k = 0; k < 3; ++k) {
            int idx = (k * 8 + j) * 4; // dword within the group's 96
            float4 v = *reinterpret_cast<const float4*>(&sg[idx]);
            *reinterpret_cast<float4*>(&ob[obase + idx]) = v;
        }
    }
#undef STEP_LDS
}

extern "C" void kernel_launch(void* const* d_in, const int* in_sizes, int n_in,
                              void* d_out, int out_size, void* d_ws, size_t ws_size,
                              hipStream_t stream) {
    const float* feats = (const float*)d_in[0];
    const float* alpha = (const float*)d_in[1];
    const float* trans = (const float*)d_in[2];
    float* out = (float*)d_out;

    int B = in_sizes[0] / (T_STEPS * CC);   // 8192 (same convention as verified round-0 kernel)

    int threads = B * NCHUNK * 8;           // 8 lanes per (row, chunk)
    int block   = 256;
    int grid    = (threads + block - 1) / block;

    hipLaunchKernelGGL(transfer_kernel, dim3(grid), dim3(block), 0, stream,
                       feats, alpha, trans, out, B);
}